// Round 4
// baseline (1223.882 us; speedup 1.0000x reference)
//
#include <hip/hip_runtime.h>
#include <hip/hip_bf16.h>

#define B_  64
#define S_  128
#define WP_ 18
#define K_  3
#define E_  128
#define H_  256
#define L_  4
#define T_  50

typedef __hip_bfloat16 bf16;
typedef float f32x2 __attribute__((ext_vector_type(2)));

__device__ __forceinline__ float b2f(bf16 x) { return __bfloat162float(x); }
__device__ __forceinline__ bf16  f2b(float x) { return __float2bfloat16(x); }

__device__ __forceinline__ float fast_sigmoid(float x) {
    return 1.f / (1.f + __expf(-x));
}
__device__ __forceinline__ float fast_tanh(float x) {
    float a = fminf(fmaxf(2.f * x, -30.f), 30.f);
    float e = __expf(a);
    return (e - 1.f) / (e + 1.f);
}
__device__ __forceinline__ f32x2 mk2(float a, float b) { f32x2 r; r.x = a; r.y = b; return r; }

// ---------------------------------------------------------------- zero sync counters
__global__ void k_zero_cnt(int* __restrict__ cnt) {
    if (threadIdx.x < 32) cnt[threadIdx.x] = 0;
}

// ---------------------------------------------------------------- transpose (f32 -> bf16)
__global__ void k_transpose(const float* __restrict__ src, bf16* __restrict__ dst,
                            int R, int C) {
    int i = blockIdx.x * 256 + threadIdx.x;
    if (i >= R * C) return;
    int r = i / C, c = i % C;
    dst[c * R + r] = f2b(src[i]);
}

// ---------------------------------------------------------------- pack Whh for LDS residency
// dst[(q*256 + j)*264 + k] = Whh[colO(q,j)][k], colO = (j>>6)*256 + q*64 + (j&63)
__global__ void k_pack_whh(const float* __restrict__ src, bf16* __restrict__ dst) {
    int idx = blockIdx.x * 256 + threadIdx.x;   // over 4*256*256
    if (idx >= 4 * 256 * 256) return;
    int q = idx >> 16;
    int r = idx & 65535;
    int j = r >> 8, k = r & 255;
    int colO = ((j >> 6) << 8) + (q << 6) + (j & 63);
    dst[(q * 256 + j) * 264 + k] = f2b(src[colO * 256 + k]);
}

// ---------------------------------------------------------------- char CNN
__global__ void k_charcnn(const int* __restrict__ char_ids,
                          const float* __restrict__ char_emb,
                          const float* __restrict__ cnn_w,
                          const float* __restrict__ cnn_b,
                          float* __restrict__ out_char) {
    const int CE_S = 132;
    const int W_S  = 388;
    __shared__ float ce[WP_ * 132];
    __shared__ float w[L_ * 388];
    __shared__ float bias[L_];
    int idx = blockIdx.x;            // b*S + s
    int t   = threadIdx.x;           // 0..63
    const int* ids = char_ids + idx * WP_;
    for (int i = t; i < WP_ * E_; i += 64) {
        int r = i >> 7, e = i & 127;
        ce[r * CE_S + e] = char_emb[ids[r] * E_ + e];
    }
    for (int i = t; i < L_ * K_ * E_; i += 64) {
        int r = i / (K_ * E_), e = i % (K_ * E_);
        w[r * W_S + e] = cnn_w[i];
    }
    if (t < L_) bias[t] = cnn_b[t];
    __syncthreads();
    int pos = t >> 2, c = t & 3;     // 16 positions x 4 channels
    float acc = 0.f;
    const float* wr = &w[c * W_S];
    #pragma unroll
    for (int i = 0; i < K_; ++i) {
        const float* cr = &ce[(pos + i) * CE_S];
        #pragma unroll 8
        for (int e = 0; e < E_; ++e) acc = fmaf(cr[e], wr[i * E_ + e], acc);
    }
    acc += bias[c];
    #pragma unroll
    for (int off = 4; off < 64; off <<= 1) acc = fmaxf(acc, __shfl_xor(acc, off));
    if (t < L_) out_char[idx * L_ + t] = acc;
}

// ---------------------------------------------------------------- input proj
// igp[((s*16 + bg)*1024 + col)*4 + (b&3)] = b[col] + sum_k we[b,s,k]*WihT[k,col]
__global__ void k_input_proj(const int* __restrict__ word_ids,
                             const float* __restrict__ word_emb,
                             const bf16* __restrict__ wihT_f, const float* __restrict__ b_f,
                             const bf16* __restrict__ wihT_b, const float* __restrict__ b_b,
                             bf16* __restrict__ igp_f, bf16* __restrict__ igp_b) {
    int dir = blockIdx.y;
    const bf16* wihT = dir ? wihT_b : wihT_f;
    const float* bb  = dir ? b_b    : b_f;
    bf16* igp        = dir ? igp_b  : igp_f;
    __shared__ float x[8][128];
    int t  = threadIdx.x;            // 0..255
    int r0 = blockIdx.x * 8;         // 8 rows (s*B+b) per block
    for (int i = t; i < 8 * 128; i += 256) {
        int rr = i >> 7, e = i & 127;
        int r = r0 + rr;
        int s = r >> 6, b = r & 63;
        int wid = word_ids[b * S_ + s];
        x[rr][e] = word_emb[(size_t)wid * E_ + e];
    }
    __syncthreads();
    int j = t;
    float acc[4][8];
    #pragma unroll
    for (int cj = 0; cj < 4; ++cj) {
        float bv = bb[j + cj * 256];
        #pragma unroll
        for (int rr = 0; rr < 8; ++rr) acc[cj][rr] = bv;
    }
    for (int k = 0; k < 128; ++k) {
        float wv[4];
        #pragma unroll
        for (int cj = 0; cj < 4; ++cj) wv[cj] = b2f(wihT[k * 1024 + j + cj * 256]);
        #pragma unroll
        for (int rr = 0; rr < 8; ++rr) {
            float xv = x[rr][k];
            #pragma unroll
            for (int cj = 0; cj < 4; ++cj) acc[cj][rr] = fmaf(xv, wv[cj], acc[cj][rr]);
        }
    }
    #pragma unroll
    for (int cj = 0; cj < 4; ++cj)
        #pragma unroll
        for (int rr = 0; rr < 8; ++rr) {
            int r = r0 + rr;
            int s = r >> 6, b = r & 63;
            int col = j + cj * 256;
            igp[(((size_t)s * 16 + (b >> 2)) * 1024 + col) * 4 + (b & 3)] = f2b(acc[cj][rr]);
        }
}

// ---------------------------------------------------------------- recurrence (4-block groups)
// grid 128 = 32 groups x 4 quarter-blocks. Group = (dir, 4 batches). Block q owns
// h-indices [q*64, q*64+64) => 256 columns (4 gates), weights LDS-resident (132 KB).
// Per step: z from LDS (pk-fma over chain pairs) -> gates -> exchange h quarters
// through hs[] with device-scope atomics + per-group counter.
__global__ __launch_bounds__(512) void k_lstm_rec(
        const bf16* __restrict__ igp_f, const bf16* __restrict__ igp_b,
        const bf16* __restrict__ wp_f, const bf16* __restrict__ wp_b,
        float* __restrict__ hf, float* __restrict__ hb,
        int* __restrict__ cnt) {
    __shared__ bf16  Wl[256 * 264];         // 135168 B
    __shared__ float H2f[2 * 264 * 2];      // [cp][k][chain parity], 4224 B
    __shared__ float ZB[256 * 4];           // [j][c], 4096 B

    int p    = blockIdx.x;
    int xcd  = p & 7, slot = p >> 3;
    int gid  = xcd * 4 + (slot >> 2);       // 0..31
    int q    = slot & 3;                    // h-quarter
    int dir  = gid >> 4;
    int bg   = gid & 15;                    // batch group (4 batches)

    const bf16* igp = dir ? igp_b : igp_f;
    const bf16* wp  = dir ? wp_b  : wp_f;
    float* hs       = dir ? hb    : hf;

    int t = threadIdx.x;                    // 0..511
    int j = t >> 1, cp = t & 1;             // column-in-block, chain pair
    int colO = ((j >> 6) << 8) + (q << 6) + (j & 63);

    // load weights for this quarter into LDS (contiguous 135168 B region)
    {
        const uint4* srcv = (const uint4*)(wp + (size_t)q * 256 * 264);
        uint4* dstv = (uint4*)Wl;
        for (int u = t; u < 256 * 33; u += 512) dstv[u] = srcv[u];
    }
    for (int u = t; u < 2 * 264 * 2; u += 512) H2f[u] = 0.f;
    float c_reg = 0.f;
    __syncthreads();

    const bf16*  wrow  = &Wl[j * 264];
    const float* hbase = &H2f[cp * 264 * 2];

    for (int step = 0; step < S_; ++step) {
        int sa = dir ? (S_ - 1 - step) : step;

        // ---- z phase: 2 chains per thread via packed fma
        uint igu = *(const uint*)(igp + ((((size_t)sa * 16 + bg) * 1024 + colO) * 4 + 2 * cp));
        f32x2 z2 = mk2(__uint_as_float(igu << 16), __uint_as_float(igu & 0xffff0000u));
        #pragma unroll 8
        for (int kb = 0; kb < 32; ++kb) {
            uint4 wv = *(const uint4*)(wrow + kb * 8);
            const float4* hp = (const float4*)(hbase + kb * 16);
            float4 p0 = hp[0], p1 = hp[1], p2 = hp[2], p3 = hp[3];
            float w0 = __uint_as_float(wv.x << 16), w1 = __uint_as_float(wv.x & 0xffff0000u);
            float w2 = __uint_as_float(wv.y << 16), w3 = __uint_as_float(wv.y & 0xffff0000u);
            float w4 = __uint_as_float(wv.z << 16), w5 = __uint_as_float(wv.z & 0xffff0000u);
            float w6 = __uint_as_float(wv.w << 16), w7 = __uint_as_float(wv.w & 0xffff0000u);
            z2 = __builtin_elementwise_fma(mk2(w0, w0), mk2(p0.x, p0.y), z2);
            z2 = __builtin_elementwise_fma(mk2(w1, w1), mk2(p0.z, p0.w), z2);
            z2 = __builtin_elementwise_fma(mk2(w2, w2), mk2(p1.x, p1.y), z2);
            z2 = __builtin_elementwise_fma(mk2(w3, w3), mk2(p1.z, p1.w), z2);
            z2 = __builtin_elementwise_fma(mk2(w4, w4), mk2(p2.x, p2.y), z2);
            z2 = __builtin_elementwise_fma(mk2(w5, w5), mk2(p2.z, p2.w), z2);
            z2 = __builtin_elementwise_fma(mk2(w6, w6), mk2(p3.x, p3.y), z2);
            z2 = __builtin_elementwise_fma(mk2(w7, w7), mk2(p3.z, p3.w), z2);
        }
        *(f32x2*)&ZB[j * 4 + 2 * cp] = z2;
        __syncthreads();

        // ---- gate phase: 256 threads = 64 h-idx x 4 chains
        if (t < 256) {
            int i = t >> 2, c = t & 3;
            float zi = ZB[(i)       * 4 + c];
            float zf = ZB[(64 + i)  * 4 + c];
            float zg = ZB[(128 + i) * 4 + c];
            float zo = ZB[(192 + i) * 4 + c];
            float si = fast_sigmoid(zi);
            float sf = fast_sigmoid(zf);
            float so = fast_sigmoid(zo);
            float tg = fast_tanh(zg);
            c_reg = sf * c_reg + si * tg;
            float hn = so * fast_tanh(c_reg);
            int hidx = (q << 6) + i;
            H2f[((c >> 1) * 264 + hidx) * 2 + (c & 1)] = hn;
            __hip_atomic_store(hs + ((size_t)sa * 64 + (bg * 4 + c)) * 256 + hidx, hn,
                               __ATOMIC_RELAXED, __HIP_MEMORY_SCOPE_AGENT);
        }
        __syncthreads();

        // ---- publish + wait for siblings
        if (t == 0) {
            __hip_atomic_fetch_add(cnt + gid, 1, __ATOMIC_RELEASE, __HIP_MEMORY_SCOPE_AGENT);
            int target = 4 * (step + 1);
            int guard = 0;
            while (__hip_atomic_load(cnt + gid, __ATOMIC_ACQUIRE, __HIP_MEMORY_SCOPE_AGENT) < target
                   && ++guard < (1 << 22)) {
                __builtin_amdgcn_s_sleep(1);
            }
        }
        __syncthreads();

        // ---- pull 3 remote quarters into LDS
        for (int u = t; u < 768; u += 512) {
            int rq = u >> 8;
            int qq = rq + (rq >= q);
            int c  = (u >> 6) & 3, i2 = u & 63;
            int hidx = (qq << 6) + i2;
            float v = __hip_atomic_load(hs + ((size_t)sa * 64 + (bg * 4 + c)) * 256 + hidx,
                                        __ATOMIC_RELAXED, __HIP_MEMORY_SCOPE_AGENT);
            H2f[((c >> 1) * 264 + hidx) * 2 + (c & 1)] = v;
        }
        __syncthreads();
    }
}

// ---------------------------------------------------------------- tag linear
__global__ void k_tag_linear(const float* __restrict__ hf, const float* __restrict__ hb,
                             const float* __restrict__ out_w, const float* __restrict__ out_b,
                             float* __restrict__ tag) {
    int bs = blockIdx.x;             // b*S + s
    int b = bs >> 7, s = bs & 127;
    __shared__ float hv[512];
    int t = threadIdx.x;             // 0..63
    const float* hfr = hf + ((size_t)s * B_ + b) * 256;
    const float* hbr = hb + ((size_t)s * B_ + b) * 256;
    for (int i = t; i < 256; i += 64) { hv[i] = hfr[i]; hv[256 + i] = hbr[i]; }
    __syncthreads();
    if (t < T_) {
        float acc = out_b[t];
        #pragma unroll 8
        for (int k = 0; k < 512; ++k) acc = fmaf(hv[k], out_w[t * 512 + k], acc);
        tag[((size_t)b * T_ + t) * S_ + s] = acc;
    }
}

// ---------------------------------------------------------------- log_softmax over S (axis=1)
__global__ void k_log_softmax(const float* __restrict__ tag, float* __restrict__ out) {
    int wid  = (blockIdx.x * 256 + threadIdx.x) >> 6;   // one wave per (b,t)
    int lane = threadIdx.x & 63;
    if (wid >= B_ * T_) return;
    int b = wid / T_, t = wid % T_;
    const float* row = tag + (size_t)wid * S_;
    float v0 = row[lane], v1 = row[lane + 64];
    float m = fmaxf(v0, v1);
    #pragma unroll
    for (int off = 32; off; off >>= 1) m = fmaxf(m, __shfl_xor(m, off));
    float e = expf(v0 - m) + expf(v1 - m);
    #pragma unroll
    for (int off = 32; off; off >>= 1) e += __shfl_xor(e, off);
    float lse = m + logf(e);
    out[((size_t)b * S_ + lane)      * T_ + t] = v0 - lse;
    out[((size_t)b * S_ + lane + 64) * T_ + t] = v1 - lse;
}

// ---------------------------------------------------------------- launch
extern "C" void kernel_launch(void* const* d_in, const int* in_sizes, int n_in,
                              void* d_out, int out_size, void* d_ws, size_t ws_size,
                              hipStream_t stream) {
    const int*   char_ids = (const int*)d_in[0];
    const int*   word_ids = (const int*)d_in[1];
    const float* char_emb = (const float*)d_in[2];
    const float* word_emb = (const float*)d_in[3];
    const float* cnn_w    = (const float*)d_in[4];
    const float* cnn_b    = (const float*)d_in[5];
    const float* wih_f    = (const float*)d_in[6];
    const float* whh_f    = (const float*)d_in[7];
    const float* b_f      = (const float*)d_in[8];
    const float* wih_b    = (const float*)d_in[9];
    const float* whh_b    = (const float*)d_in[10];
    const float* b_b      = (const float*)d_in[11];
    const float* out_w    = (const float*)d_in[12];
    const float* out_b    = (const float*)d_in[13];
    float* out = (float*)d_out;
    char* ws   = (char*)d_ws;

    size_t o = 0;
    bf16* wihT_f = (bf16*)(ws + o); o += (size_t)128 * 1024 * 2;
    bf16* wihT_b = (bf16*)(ws + o); o += (size_t)128 * 1024 * 2;
    bf16* wp_f   = (bf16*)(ws + o); o += (size_t)4 * 256 * 264 * 2;
    bf16* wp_b   = (bf16*)(ws + o); o += (size_t)4 * 256 * 264 * 2;
    bf16* igp_f  = (bf16*)(ws + o); o += (size_t)S_ * B_ * 1024 * 2;
    bf16* igp_b  = (bf16*)(ws + o); o += (size_t)S_ * B_ * 1024 * 2;
    float* hf    = (float*)(ws + o); o += (size_t)S_ * B_ * 256 * 4;
    float* hb    = (float*)(ws + o); o += (size_t)S_ * B_ * 256 * 4;
    float* tag   = (float*)(ws + o); o += (size_t)B_ * T_ * S_ * 4;
    int*   cnt   = (int*)(ws + o);  o += 32 * sizeof(int);

    k_zero_cnt<<<1, 64, 0, stream>>>(cnt);
    k_transpose<<<512, 256, 0, stream>>>(wih_f, wihT_f, 1024, 128);
    k_transpose<<<512, 256, 0, stream>>>(wih_b, wihT_b, 1024, 128);
    k_pack_whh<<<1024, 256, 0, stream>>>(whh_f, wp_f);
    k_pack_whh<<<1024, 256, 0, stream>>>(whh_b, wp_b);
    k_input_proj<<<dim3(1024, 2), 256, 0, stream>>>(word_ids, word_emb,
                                                    wihT_f, b_f, wihT_b, b_b, igp_f, igp_b);
    k_charcnn<<<B_ * S_, 64, 0, stream>>>(char_ids, char_emb, cnn_w, cnn_b,
                                          out + (size_t)B_ * S_ * T_);
    k_lstm_rec<<<128, 512, 0, stream>>>(igp_f, igp_b, wp_f, wp_b, hf, hb, cnt);
    k_tag_linear<<<B_ * S_, 64, 0, stream>>>(hf, hb, out_w, out_b, tag);
    k_log_softmax<<<(B_ * T_ + 3) / 4, 256, 0, stream>>>(tag, out);
}

// Round 5
// 1151.610 us; speedup vs baseline: 1.0628x; 1.0628x over previous
//
#include <hip/hip_runtime.h>
#include <hip/hip_bf16.h>

#define B_  64
#define S_  128
#define WP_ 18
#define K_  3
#define E_  128
#define H_  256
#define L_  4
#define T_  50

typedef __hip_bfloat16 bf16;
typedef float f32x2 __attribute__((ext_vector_type(2)));

__device__ __forceinline__ float b2f(bf16 x) { return __bfloat162float(x); }
__device__ __forceinline__ bf16  f2b(float x) { return __float2bfloat16(x); }

__device__ __forceinline__ float fast_sigmoid(float x) {
    return 1.f / (1.f + __expf(-x));
}
__device__ __forceinline__ float fast_tanh(float x) {
    float a = fminf(fmaxf(2.f * x, -30.f), 30.f);
    float e = __expf(a);
    return (e - 1.f) / (e + 1.f);
}
__device__ __forceinline__ f32x2 mk2(float a, float b) { f32x2 r; r.x = a; r.y = b; return r; }

// ---------------------------------------------------------------- zero sync counters (padded: 1 per 64 ints)
__global__ void k_zero_cnt(int* __restrict__ cnt) {
    int i = blockIdx.x * 256 + threadIdx.x;
    if (i < 32 * 64) cnt[i] = 0;
}

// ---------------------------------------------------------------- transpose (f32 -> bf16)
__global__ void k_transpose(const float* __restrict__ src, bf16* __restrict__ dst,
                            int R, int C) {
    int i = blockIdx.x * 256 + threadIdx.x;
    if (i >= R * C) return;
    int r = i / C, c = i % C;
    dst[c * R + r] = f2b(src[i]);
}

// ---------------------------------------------------------------- pack Whh for LDS residency
// dst[(q*256 + j)*264 + k] = Whh[colO(q,j)][k], colO = (j>>6)*256 + q*64 + (j&63)
__global__ void k_pack_whh(const float* __restrict__ src, bf16* __restrict__ dst) {
    int idx = blockIdx.x * 256 + threadIdx.x;   // over 4*256*256
    if (idx >= 4 * 256 * 256) return;
    int q = idx >> 16;
    int r = idx & 65535;
    int j = r >> 8, k = r & 255;
    int colO = ((j >> 6) << 8) + (q << 6) + (j & 63);
    dst[(q * 256 + j) * 264 + k] = f2b(src[colO * 256 + k]);
}

// ---------------------------------------------------------------- char CNN
__global__ void k_charcnn(const int* __restrict__ char_ids,
                          const float* __restrict__ char_emb,
                          const float* __restrict__ cnn_w,
                          const float* __restrict__ cnn_b,
                          float* __restrict__ out_char) {
    const int CE_S = 132;
    const int W_S  = 388;
    __shared__ float ce[WP_ * 132];
    __shared__ float w[L_ * 388];
    __shared__ float bias[L_];
    int idx = blockIdx.x;            // b*S + s
    int t   = threadIdx.x;           // 0..63
    const int* ids = char_ids + idx * WP_;
    for (int i = t; i < WP_ * E_; i += 64) {
        int r = i >> 7, e = i & 127;
        ce[r * CE_S + e] = char_emb[ids[r] * E_ + e];
    }
    for (int i = t; i < L_ * K_ * E_; i += 64) {
        int r = i / (K_ * E_), e = i % (K_ * E_);
        w[r * W_S + e] = cnn_w[i];
    }
    if (t < L_) bias[t] = cnn_b[t];
    __syncthreads();
    int pos = t >> 2, c = t & 3;     // 16 positions x 4 channels
    float acc = 0.f;
    const float* wr = &w[c * W_S];
    #pragma unroll
    for (int i = 0; i < K_; ++i) {
        const float* cr = &ce[(pos + i) * CE_S];
        #pragma unroll 8
        for (int e = 0; e < E_; ++e) acc = fmaf(cr[e], wr[i * E_ + e], acc);
    }
    acc += bias[c];
    #pragma unroll
    for (int off = 4; off < 64; off <<= 1) acc = fmaxf(acc, __shfl_xor(acc, off));
    if (t < L_) out_char[idx * L_ + t] = acc;
}

// ---------------------------------------------------------------- input proj
// igp[((s*16 + bg)*1024 + col)*4 + (b&3)] = b[col] + sum_k we[b,s,k]*WihT[k,col]
__global__ void k_input_proj(const int* __restrict__ word_ids,
                             const float* __restrict__ word_emb,
                             const bf16* __restrict__ wihT_f, const float* __restrict__ b_f,
                             const bf16* __restrict__ wihT_b, const float* __restrict__ b_b,
                             bf16* __restrict__ igp_f, bf16* __restrict__ igp_b) {
    int dir = blockIdx.y;
    const bf16* wihT = dir ? wihT_b : wihT_f;
    const float* bb  = dir ? b_b    : b_f;
    bf16* igp        = dir ? igp_b  : igp_f;
    __shared__ float x[8][128];
    int t  = threadIdx.x;            // 0..255
    int r0 = blockIdx.x * 8;         // 8 rows (s*B+b) per block
    for (int i = t; i < 8 * 128; i += 256) {
        int rr = i >> 7, e = i & 127;
        int r = r0 + rr;
        int s = r >> 6, b = r & 63;
        int wid = word_ids[b * S_ + s];
        x[rr][e] = word_emb[(size_t)wid * E_ + e];
    }
    __syncthreads();
    int j = t;
    float acc[4][8];
    #pragma unroll
    for (int cj = 0; cj < 4; ++cj) {
        float bv = bb[j + cj * 256];
        #pragma unroll
        for (int rr = 0; rr < 8; ++rr) acc[cj][rr] = bv;
    }
    for (int k = 0; k < 128; ++k) {
        float wv[4];
        #pragma unroll
        for (int cj = 0; cj < 4; ++cj) wv[cj] = b2f(wihT[k * 1024 + j + cj * 256]);
        #pragma unroll
        for (int rr = 0; rr < 8; ++rr) {
            float xv = x[rr][k];
            #pragma unroll
            for (int cj = 0; cj < 4; ++cj) acc[cj][rr] = fmaf(xv, wv[cj], acc[cj][rr]);
        }
    }
    #pragma unroll
    for (int cj = 0; cj < 4; ++cj)
        #pragma unroll
        for (int rr = 0; rr < 8; ++rr) {
            int r = r0 + rr;
            int s = r >> 6, b = r & 63;
            int col = j + cj * 256;
            igp[(((size_t)s * 16 + (b >> 2)) * 1024 + col) * 4 + (b & 3)] = f2b(acc[cj][rr]);
        }
}

// ---------------------------------------------------------------- recurrence (4-block groups)
// grid 128 = 32 groups x 4 quarter-blocks on one XCD each. Exchange via compact
// xbuf + per-group padded counters (release/acquire), ig prefetch.
__global__ __launch_bounds__(512) void k_lstm_rec(
        const bf16* __restrict__ igp_f, const bf16* __restrict__ igp_b,
        const bf16* __restrict__ wp_f, const bf16* __restrict__ wp_b,
        float* __restrict__ hf, float* __restrict__ hb,
        float* __restrict__ xbuf, int* __restrict__ cnt) {
    __shared__ bf16  Wl[256 * 264];         // 135168 B
    __shared__ float H2f[2 * 264 * 2];      // [cp][k][chain parity]
    __shared__ float ZB[256 * 4];           // [j][c]

    int p    = blockIdx.x;
    int xcd  = p & 7, slot = p >> 3;
    int gid  = xcd * 4 + (slot >> 2);       // 0..31
    int q    = slot & 3;                    // h-quarter
    int dir  = gid >> 4;
    int bg   = gid & 15;                    // batch group (4 batches)

    const bf16* igp = dir ? igp_b : igp_f;
    const bf16* wp  = dir ? wp_b  : wp_f;
    float* hs       = dir ? hb    : hf;
    float* xg       = xbuf + gid * 1024;    // [q][c][i]
    int*   cg       = cnt + gid * 64;       // padded counter

    int t = threadIdx.x;                    // 0..511
    int j = t >> 1, cp = t & 1;             // column-in-block, chain pair
    int colO = ((j >> 6) << 8) + (q << 6) + (j & 63);

    {
        const uint4* srcv = (const uint4*)(wp + (size_t)q * 256 * 264);
        uint4* dstv = (uint4*)Wl;
        for (int u = t; u < 256 * 33; u += 512) dstv[u] = srcv[u];
    }
    for (int u = t; u < 2 * 264 * 2; u += 512) H2f[u] = 0.f;
    float c_reg = 0.f;
    __syncthreads();

    const bf16*  wrow  = &Wl[j * 264];
    const float* hbase = &H2f[cp * 264 * 2];

    int sa0 = dir ? (S_ - 1) : 0;
    uint igu = *(const uint*)(igp + ((((size_t)sa0 * 16 + bg) * 1024 + colO) * 4 + 2 * cp));

    for (int step = 0; step < S_; ++step) {
        int sa = dir ? (S_ - 1 - step) : step;

        // ---- z phase: 2 chains per thread via packed fma
        f32x2 z2 = mk2(__uint_as_float(igu << 16), __uint_as_float(igu & 0xffff0000u));
        #pragma unroll 8
        for (int kb = 0; kb < 32; ++kb) {
            uint4 wv = *(const uint4*)(wrow + kb * 8);
            const float4* hp = (const float4*)(hbase + kb * 16);
            float4 p0 = hp[0], p1 = hp[1], p2 = hp[2], p3 = hp[3];
            float w0 = __uint_as_float(wv.x << 16), w1 = __uint_as_float(wv.x & 0xffff0000u);
            float w2 = __uint_as_float(wv.y << 16), w3 = __uint_as_float(wv.y & 0xffff0000u);
            float w4 = __uint_as_float(wv.z << 16), w5 = __uint_as_float(wv.z & 0xffff0000u);
            float w6 = __uint_as_float(wv.w << 16), w7 = __uint_as_float(wv.w & 0xffff0000u);
            z2 = __builtin_elementwise_fma(mk2(w0, w0), mk2(p0.x, p0.y), z2);
            z2 = __builtin_elementwise_fma(mk2(w1, w1), mk2(p0.z, p0.w), z2);
            z2 = __builtin_elementwise_fma(mk2(w2, w2), mk2(p1.x, p1.y), z2);
            z2 = __builtin_elementwise_fma(mk2(w3, w3), mk2(p1.z, p1.w), z2);
            z2 = __builtin_elementwise_fma(mk2(w4, w4), mk2(p2.x, p2.y), z2);
            z2 = __builtin_elementwise_fma(mk2(w5, w5), mk2(p2.z, p2.w), z2);
            z2 = __builtin_elementwise_fma(mk2(w6, w6), mk2(p3.x, p3.y), z2);
            z2 = __builtin_elementwise_fma(mk2(w7, w7), mk2(p3.z, p3.w), z2);
        }
        *(f32x2*)&ZB[j * 4 + 2 * cp] = z2;

        // prefetch next step's ig word (latency hides under gate+sync phases)
        if (step + 1 < S_) {
            int sn = dir ? (S_ - 2 - step) : (step + 1);
            igu = *(const uint*)(igp + ((((size_t)sn * 16 + bg) * 1024 + colO) * 4 + 2 * cp));
        }
        __syncthreads();

        // ---- gate phase: 256 threads = 64 h-idx x 4 chains
        if (t < 256) {
            int i = t >> 2, c = t & 3;
            float zi = ZB[(i)       * 4 + c];
            float zf = ZB[(64 + i)  * 4 + c];
            float zg = ZB[(128 + i) * 4 + c];
            float zo = ZB[(192 + i) * 4 + c];
            float si = fast_sigmoid(zi);
            float sf = fast_sigmoid(zf);
            float so = fast_sigmoid(zo);
            float tg = fast_tanh(zg);
            c_reg = sf * c_reg + si * tg;
            float hn = so * fast_tanh(c_reg);
            int hidx = (q << 6) + i;
            H2f[((c >> 1) * 264 + hidx) * 2 + (c & 1)] = hn;
            __hip_atomic_store(xg + q * 256 + c * 64 + i, hn,
                               __ATOMIC_RELAXED, __HIP_MEMORY_SCOPE_AGENT);
            hs[((size_t)sa * 64 + (bg * 4 + c)) * 256 + hidx] = hn;   // plain store
        }
        __syncthreads();

        // ---- publish + wait for siblings (padded counter, relaxed poll)
        if (t == 0) {
            __hip_atomic_fetch_add(cg, 1, __ATOMIC_RELEASE, __HIP_MEMORY_SCOPE_AGENT);
            int target = 4 * (step + 1);
            int guard = 0;
            while (__hip_atomic_load(cg, __ATOMIC_RELAXED, __HIP_MEMORY_SCOPE_AGENT) < target
                   && ++guard < (1 << 24)) {
                __builtin_amdgcn_s_sleep(2);
            }
            (void)__hip_atomic_load(cg, __ATOMIC_ACQUIRE, __HIP_MEMORY_SCOPE_AGENT);
        }
        __syncthreads();

        // ---- pull 3 remote quarters into LDS
        for (int u = t; u < 768; u += 512) {
            int rq = u >> 8;
            int qq = rq + (rq >= q);
            int c  = (u >> 6) & 3, i2 = u & 63;
            int hidx = (qq << 6) + i2;
            float v = __hip_atomic_load(xg + qq * 256 + c * 64 + i2,
                                        __ATOMIC_RELAXED, __HIP_MEMORY_SCOPE_AGENT);
            H2f[((c >> 1) * 264 + hidx) * 2 + (c & 1)] = v;
        }
        __syncthreads();
    }
}

// ---------------------------------------------------------------- tag linear
__global__ void k_tag_linear(const float* __restrict__ hf, const float* __restrict__ hb,
                             const float* __restrict__ out_w, const float* __restrict__ out_b,
                             float* __restrict__ tag) {
    int bs = blockIdx.x;             // b*S + s
    int b = bs >> 7, s = bs & 127;
    __shared__ float hv[512];
    int t = threadIdx.x;             // 0..63
    const float* hfr = hf + ((size_t)s * B_ + b) * 256;
    const float* hbr = hb + ((size_t)s * B_ + b) * 256;
    for (int i = t; i < 256; i += 64) { hv[i] = hfr[i]; hv[256 + i] = hbr[i]; }
    __syncthreads();
    if (t < T_) {
        float acc = out_b[t];
        #pragma unroll 8
        for (int k = 0; k < 512; ++k) acc = fmaf(hv[k], out_w[t * 512 + k], acc);
        tag[((size_t)b * T_ + t) * S_ + s] = acc;
    }
}

// ---------------------------------------------------------------- log_softmax over S (axis=1)
__global__ void k_log_softmax(const float* __restrict__ tag, float* __restrict__ out) {
    int wid  = (blockIdx.x * 256 + threadIdx.x) >> 6;   // one wave per (b,t)
    int lane = threadIdx.x & 63;
    if (wid >= B_ * T_) return;
    int b = wid / T_, t = wid % T_;
    const float* row = tag + (size_t)wid * S_;
    float v0 = row[lane], v1 = row[lane + 64];
    float m = fmaxf(v0, v1);
    #pragma unroll
    for (int off = 32; off; off >>= 1) m = fmaxf(m, __shfl_xor(m, off));
    float e = expf(v0 - m) + expf(v1 - m);
    #pragma unroll
    for (int off = 32; off; off >>= 1) e += __shfl_xor(e, off);
    float lse = m + logf(e);
    out[((size_t)b * S_ + lane)      * T_ + t] = v0 - lse;
    out[((size_t)b * S_ + lane + 64) * T_ + t] = v1 - lse;
}

// ---------------------------------------------------------------- launch
extern "C" void kernel_launch(void* const* d_in, const int* in_sizes, int n_in,
                              void* d_out, int out_size, void* d_ws, size_t ws_size,
                              hipStream_t stream) {
    const int*   char_ids = (const int*)d_in[0];
    const int*   word_ids = (const int*)d_in[1];
    const float* char_emb = (const float*)d_in[2];
    const float* word_emb = (const float*)d_in[3];
    const float* cnn_w    = (const float*)d_in[4];
    const float* cnn_b    = (const float*)d_in[5];
    const float* wih_f    = (const float*)d_in[6];
    const float* whh_f    = (const float*)d_in[7];
    const float* b_f      = (const float*)d_in[8];
    const float* wih_b    = (const float*)d_in[9];
    const float* whh_b    = (const float*)d_in[10];
    const float* b_b      = (const float*)d_in[11];
    const float* out_w    = (const float*)d_in[12];
    const float* out_b    = (const float*)d_in[13];
    float* out = (float*)d_out;
    char* ws   = (char*)d_ws;

    size_t o = 0;
    bf16* wihT_f = (bf16*)(ws + o); o += (size_t)128 * 1024 * 2;
    bf16* wihT_b = (bf16*)(ws + o); o += (size_t)128 * 1024 * 2;
    bf16* wp_f   = (bf16*)(ws + o); o += (size_t)4 * 256 * 264 * 2;
    bf16* wp_b   = (bf16*)(ws + o); o += (size_t)4 * 256 * 264 * 2;
    bf16* igp_f  = (bf16*)(ws + o); o += (size_t)S_ * B_ * 1024 * 2;
    bf16* igp_b  = (bf16*)(ws + o); o += (size_t)S_ * B_ * 1024 * 2;
    float* hf    = (float*)(ws + o); o += (size_t)S_ * B_ * 256 * 4;
    float* hb    = (float*)(ws + o); o += (size_t)S_ * B_ * 256 * 4;
    float* tag   = (float*)(ws + o); o += (size_t)B_ * T_ * S_ * 4;
    float* xbuf  = (float*)(ws + o); o += (size_t)32 * 1024 * 4;
    int*   cnt   = (int*)(ws + o);  o += (size_t)32 * 64 * sizeof(int);

    k_zero_cnt<<<8, 256, 0, stream>>>(cnt);
    k_transpose<<<512, 256, 0, stream>>>(wih_f, wihT_f, 1024, 128);
    k_transpose<<<512, 256, 0, stream>>>(wih_b, wihT_b, 1024, 128);
    k_pack_whh<<<1024, 256, 0, stream>>>(whh_f, wp_f);
    k_pack_whh<<<1024, 256, 0, stream>>>(whh_b, wp_b);
    k_input_proj<<<dim3(1024, 2), 256, 0, stream>>>(word_ids, word_emb,
                                                    wihT_f, b_f, wihT_b, b_b, igp_f, igp_b);
    k_charcnn<<<B_ * S_, 64, 0, stream>>>(char_ids, char_emb, cnn_w, cnn_b,
                                          out + (size_t)B_ * S_ * T_);
    k_lstm_rec<<<128, 512, 0, stream>>>(igp_f, igp_b, wp_f, wp_b, hf, hb, xbuf, cnt);
    k_tag_linear<<<B_ * S_, 64, 0, stream>>>(hf, hb, out_w, out_b, tag);
    k_log_softmax<<<(B_ * T_ + 3) / 4, 256, 0, stream>>>(tag, out);
}